// Round 10
// baseline (166.816 us; speedup 1.0000x reference)
//
#include <hip/hip_runtime.h>

#define NVEC 65536   // B*H*W = 64*32*32
#define KCB  1024
#define DIM  128
#define HW   1024    // H*W
#define CHUNK 64
#define NCHUNKS (NVEC / CHUNK)

typedef __bf16 b16;
typedef b16 b16x8 __attribute__((ext_vector_type(8)));
typedef float f32x16 __attribute__((ext_vector_type(16)));

static __device__ __forceinline__ unsigned short f2bf(float f) {
  unsigned int x = __float_as_uint(f);
  unsigned int r = x + 0x7fffu + ((x >> 16) & 1u);   // RNE
  return (unsigned short)(r >> 16);
}

// ---- fused prep: cbt pack + out6=0.99*emw + hist=0 + ccb(f32) + cc64(f64) -
__global__ void k_prep(const float* __restrict__ cb, const float* __restrict__ emw,
                       uint4* __restrict__ cbt, float* __restrict__ ccb,
                       double* __restrict__ cc64, float* __restrict__ out6,
                       int* __restrict__ hist) {
  const int t = blockIdx.x * blockDim.x + threadIdx.x;   // 16384
  const int kc = t >> 11, u = t & 2047;
  const int code7 = u & 127, dch = u >> 7;
  const float* src = cb + (kc * 128 + code7) * 128 + dch * 8;
  const float4 x = *(const float4*)src;
  const float4 y = *(const float4*)(src + 4);
  uint4 o;
  o.x = (unsigned)f2bf(x.x) | ((unsigned)f2bf(x.y) << 16);
  o.y = (unsigned)f2bf(x.z) | ((unsigned)f2bf(x.w) << 16);
  o.z = (unsigned)f2bf(y.x) | ((unsigned)f2bf(y.y) << 16);
  o.w = (unsigned)f2bf(y.z) | ((unsigned)f2bf(y.w) << 16);
  cbt[t] = o;
  // out6 init: out6 offset is 8B- but not 16B-aligned -> float2 stores
  const float4 e0 = *(const float4*)(emw + (size_t)t * 8);
  const float4 e1 = *(const float4*)(emw + (size_t)t * 8 + 4);
  *(float2*)(out6 + (size_t)t * 8 + 0) = make_float2(0.99f * e0.x, 0.99f * e0.y);
  *(float2*)(out6 + (size_t)t * 8 + 2) = make_float2(0.99f * e0.z, 0.99f * e0.w);
  *(float2*)(out6 + (size_t)t * 8 + 4) = make_float2(0.99f * e1.x, 0.99f * e1.y);
  *(float2*)(out6 + (size_t)t * 8 + 6) = make_float2(0.99f * e1.z, 0.99f * e1.w);
  if (t < KCB) hist[t] = 0;
  if (blockIdx.x < 4) {
    const int k = blockIdx.x * 256 + threadIdx.x;
    const float* row = cb + k * DIM;
    double s = 0.0;
#pragma unroll 8
    for (int j = 0; j < DIM; ++j) {
      const double v = (double)row[j];
      s = fma(v, v, s);
    }
    cc64[k] = s;
    ccb[k] = 512.f - 0.5f * (float)s;   // bias keeps packed scores positive
  }
}

// ---- MFMA argmin + fused transpose; B-fragments from L2 (no staging loop) -
// Phase 0: stage z tile [128 d][64 hw] in LDS (padded 65). Phase 1: z_t
// full-line stores + afrag from LDS. kc-loop: B operands loaded directly
// global->reg (cbt is 256KB, L2-resident; 32 lanes x 16B = 512B coalesced)
// -- NO barriers, no vmcnt(0) drains in the loop (R8's 60% stall).
// score(bias) = 512 - cc/2 + dot straight out of the MFMA (C-in=ccb);
// positive => u32-monotone; index inverted in low 10 bits (max-tie -> min k).
__global__ __launch_bounds__(256, 2) void k_argmin3t(
    const float* __restrict__ z, const uint4* __restrict__ cbt,
    const float* __restrict__ ccb, uint2* __restrict__ pcand,
    float* __restrict__ z_t) {
  __shared__ __align__(16) float zs[128][65];          // 33.3 KB
  const int tid = threadIdx.x;
  const int l = tid & 63, wv = tid >> 6;
  const int g = l >> 5;                            // k-slice group
  const int lm = l & 31;                           // row-lane / code-lane
  const int wr = (wv & 1) * 32;
  const int wc = wv >> 1;
  const int n0 = blockIdx.x * 64;
  const int b = n0 >> 10;
  const int hwbase = n0 & (HW - 1);

  // ---- phase 0: coalesced stage of the z tile into LDS
  {
    const int hw4 = (tid & 15) * 4;
    const int dr = tid >> 4;
    const float* src = z + (size_t)b * 131072 + hwbase + hw4;
#pragma unroll
    for (int j = 0; j < 8; ++j) {
      const int d = dr + 16 * j;
      const float4 v = *(const float4*)(src + d * 1024);
      zs[d][hw4 + 0] = v.x; zs[d][hw4 + 1] = v.y;
      zs[d][hw4 + 2] = v.z; zs[d][hw4 + 3] = v.w;
    }
  }
  __syncthreads();

  // ---- phase 1a: z_t rows, full-line stores (8 lanes x 16B per 512B row)
#pragma unroll
  for (int jj = 0; jj < 2; ++jj) {
    const int row = (tid >> 3) + 32 * jj;
    float* dst = z_t + ((size_t)(n0 + row)) * 128;
#pragma unroll
    for (int j = 0; j < 4; ++j) {
      const int d = (j * 8 + (tid & 7)) * 4;
      float4 v;
      v.x = zs[d + 0][row]; v.y = zs[d + 1][row];
      v.z = zs[d + 2][row]; v.w = zs[d + 3][row];
      *(float4*)(dst + d) = v;
    }
  }
  // ---- phase 1b: afrag from LDS
  uint4 afrag[8];
  {
    const int row = wr + lm;
#pragma unroll
    for (int ks = 0; ks < 8; ++ks) {
      const int d0 = ks * 16 + g * 8;
      afrag[ks].x = (unsigned)f2bf(zs[d0 + 0][row]) | ((unsigned)f2bf(zs[d0 + 1][row]) << 16);
      afrag[ks].y = (unsigned)f2bf(zs[d0 + 2][row]) | ((unsigned)f2bf(zs[d0 + 3][row]) << 16);
      afrag[ks].z = (unsigned)f2bf(zs[d0 + 4][row]) | ((unsigned)f2bf(zs[d0 + 5][row]) << 16);
      afrag[ks].w = (unsigned)f2bf(zs[d0 + 6][row]) | ((unsigned)f2bf(zs[d0 + 7][row]) << 16);
    }
  }

  unsigned pm1[16], pm2[16];
#pragma unroll
  for (int r = 0; r < 16; ++r) { pm1[r] = 0u; pm2[r] = 0u; }

  // per-wave B base: codeset column (wc*2+f)*32 + lm, slice g
  const uint4* bp0 = cbt + g * 128 + (wc * 2 + 0) * 32 + lm;
  const uint4* bp1 = cbt + g * 128 + (wc * 2 + 1) * 32 + lm;

#pragma unroll 2
  for (int kc = 0; kc < 8; ++kc) {
    const float cv0 = ccb[kc * 128 + (wc * 2 + 0) * 32 + lm];
    const float cv1 = ccb[kc * 128 + (wc * 2 + 1) * 32 + lm];
    // issue all 16 B-loads (L2-hot, coalesced), then the MFMA chains
    uint4 b0[8], b1[8];
#pragma unroll
    for (int ks = 0; ks < 8; ++ks) {
      b0[ks] = bp0[kc * 2048 + ks * 256];
      b1[ks] = bp1[kc * 2048 + ks * 256];
    }
    f32x16 a0, a1;
#pragma unroll
    for (int j = 0; j < 16; ++j) { a0[j] = cv0; a1[j] = cv1; }
#pragma unroll
    for (int ks = 0; ks < 8; ++ks) {
      const b16x8 av = *reinterpret_cast<const b16x8*>(&afrag[ks]);
      a0 = __builtin_amdgcn_mfma_f32_32x32x16_bf16(av, *reinterpret_cast<const b16x8*>(&b0[ks]), a0, 0, 0, 0);
      a1 = __builtin_amdgcn_mfma_f32_32x32x16_bf16(av, *reinterpret_cast<const b16x8*>(&b1[ks]), a1, 0, 0, 0);
    }
    const unsigned ci0 = 1023u - (unsigned)(kc * 128 + (wc * 2) * 32 + lm);
    const unsigned ci1 = ci0 - 32u;
#pragma unroll
    for (int r = 0; r < 16; ++r) {
      {
        const unsigned uu = ((__float_as_uint(a0[r]) + 0x200u) & 0xFFFFFC00u) | ci0;
        const unsigned t = pm1[r] < uu ? pm1[r] : uu;
        pm1[r] = pm1[r] > uu ? pm1[r] : uu;
        pm2[r] = pm2[r] > t ? pm2[r] : t;
      }
      {
        const unsigned uu = ((__float_as_uint(a1[r]) + 0x200u) & 0xFFFFFC00u) | ci1;
        const unsigned t = pm1[r] < uu ? pm1[r] : uu;
        pm1[r] = pm1[r] > uu ? pm1[r] : uu;
        pm2[r] = pm2[r] > t ? pm2[r] : t;
      }
    }
  }

  // top-2 (max-order) merge across the 32 code-lanes
#pragma unroll
  for (int r = 0; r < 16; ++r) {
    unsigned u1 = pm1[r], u2 = pm2[r];
#pragma unroll
    for (int m = 1; m < 32; m <<= 1) {
      const unsigned o1 = (unsigned)__shfl_xor((int)u1, m, 64);
      const unsigned o2 = (unsigned)__shfl_xor((int)u2, m, 64);
      const unsigned s = u1 < o1 ? u1 : o1;
      u1 = u1 > o1 ? u1 : o1;
      u2 = u2 > o2 ? u2 : o2;
      u2 = u2 > s ? u2 : s;
    }
    if (lm == 0) {
      const int rowg = n0 + wr + (r & 3) + 8 * (r >> 2) + 4 * g;
      pcand[wc * NVEC + rowg] = make_uint2(u1, u2);
    }
  }
}

// ---- exact f64 rescore of ALL 4 candidates + idx + LDS histogram ----------
__global__ void k_rescore_hist(const float* __restrict__ z_t, const float* __restrict__ cb,
                               const double* __restrict__ cc64,
                               const uint2* __restrict__ pcand,
                               float* __restrict__ out1, int* __restrict__ hist) {
  __shared__ int h[KCB];
  const int tid = threadIdx.x;
#pragma unroll
  for (int j = 0; j < 4; ++j) h[tid + 256 * j] = 0;
  __syncthreads();
  const int n = blockIdx.x * 256 + tid;
  const uint2 A = pcand[n];
  const uint2 Bq = pcand[NVEC + n];
  int ks[4];
  ks[0] = 1023 - (int)(A.x & 1023u);
  ks[1] = 1023 - (int)(A.y & 1023u);
  ks[2] = 1023 - (int)(Bq.x & 1023u);
  ks[3] = 1023 - (int)(Bq.y & 1023u);
  const float4* zr = (const float4*)(z_t + (size_t)n * DIM);
  const float4* c0 = (const float4*)(cb + ks[0] * DIM);
  const float4* c1 = (const float4*)(cb + ks[1] * DIM);
  const float4* c2 = (const float4*)(cb + ks[2] * DIM);
  const float4* c3 = (const float4*)(cb + ks[3] * DIM);
  double d0 = 0.0, d1 = 0.0, d2 = 0.0, d3 = 0.0;
#pragma unroll 4
  for (int j = 0; j < DIM / 4; ++j) {
    const float4 zv = zr[j];
    const double zx = zv.x, zy = zv.y, zz = zv.z, zw = zv.w;
    const float4 a = c0[j];
    d0 = fma(zx, (double)a.x, d0); d0 = fma(zy, (double)a.y, d0);
    d0 = fma(zz, (double)a.z, d0); d0 = fma(zw, (double)a.w, d0);
    const float4 b = c1[j];
    d1 = fma(zx, (double)b.x, d1); d1 = fma(zy, (double)b.y, d1);
    d1 = fma(zz, (double)b.z, d1); d1 = fma(zw, (double)b.w, d1);
    const float4 c = c2[j];
    d2 = fma(zx, (double)c.x, d2); d2 = fma(zy, (double)c.y, d2);
    d2 = fma(zz, (double)c.z, d2); d2 = fma(zw, (double)c.w, d2);
    const float4 e = c3[j];
    d3 = fma(zx, (double)e.x, d3); d3 = fma(zy, (double)e.y, d3);
    d3 = fma(zz, (double)e.z, d3); d3 = fma(zw, (double)e.w, d3);
  }
  double s[4];
  s[0] = fma(-2.0, d0, cc64[ks[0]]);
  s[1] = fma(-2.0, d1, cc64[ks[1]]);
  s[2] = fma(-2.0, d2, cc64[ks[2]]);
  s[3] = fma(-2.0, d3, cc64[ks[3]]);
  int kw = ks[0]; double sw = s[0];
#pragma unroll
  for (int c = 1; c < 4; ++c) {
    if (s[c] < sw || (s[c] == sw && ks[c] < kw)) { sw = s[c]; kw = ks[c]; }
  }
  out1[n] = (float)kw;
  atomicAdd(&h[kw], 1);
  __syncthreads();
#pragma unroll
  for (int j = 0; j < 4; ++j) {
    const int v = h[tid + 256 * j];
    if (v) atomicAdd(&hist[tid + 256 * j], v);
  }
}

// ---- exclusive scan over 1024 bins + out5 + ntot (single block) -----------
__global__ void k_scan(const int* __restrict__ hist, const float* __restrict__ emc,
                       int* __restrict__ cursor, float* __restrict__ out5,
                       float* __restrict__ ntot) {
  __shared__ int tmp[KCB];
  __shared__ float red[16];
  const int t = threadIdx.x;
  const int v = hist[t];
  tmp[t] = v;
  __syncthreads();
  for (int off = 1; off < KCB; off <<= 1) {
    int x = 0;
    if (t >= off) x = tmp[t - off];
    __syncthreads();
    if (t >= off) tmp[t] += x;
    __syncthreads();
  }
  cursor[t] = tmp[t] - v;
  float o5 = 0.99f * emc[t] + 0.01f * (float)v;
  out5[t] = o5;
#pragma unroll
  for (int m = 32; m; m >>= 1) o5 += __shfl_xor(o5, m, 64);
  if ((t & 63) == 0) red[t >> 6] = o5;
  __syncthreads();
  if (t == 0) {
    float s = 0.f;
#pragma unroll
    for (int j = 0; j < 16; ++j) s += red[j];
    *ntot = s;
  }
}

// ---------------- scatter n's into per-code segments (+ key) ---------------
__global__ void k_scatter(const float* __restrict__ idx_f, int* __restrict__ cursor,
                          int* __restrict__ order, int* __restrict__ key) {
  const int n = blockIdx.x * blockDim.x + threadIdx.x;
  const int k = (int)idx_f[n];
  const int pos = atomicAdd(&cursor[k], 1);
  order[pos] = n;
  key[pos] = k;
}

// ---- chunk-parallel segmented reduce + quantized write + loss partial -----
__global__ __launch_bounds__(128) void k_chunkreduce_q(
    float* zq, const float* __restrict__ cb,
    const int* __restrict__ order, const int* __restrict__ key,
    float* __restrict__ out6, float* __restrict__ lossp) {
  __shared__ int so[CHUNK], sk[CHUNK];
  __shared__ float red[2];
  const int t = threadIdx.x;
  const int base = blockIdx.x * CHUNK;
  if (t < CHUNK) { so[t] = order[base + t]; sk[t] = key[base + t]; }
  __syncthreads();
  int kprev = sk[0];
  float cbv = cb[kprev * 128 + t];
  float acc = 0.f, loss = 0.f;
  int i = 0;
  while (i < CHUNK) {
    if (i + 8 <= CHUNK && sk[i] == kprev && sk[i + 7] == kprev) {
      const int n0 = so[i + 0], n1 = so[i + 1], n2 = so[i + 2], n3 = so[i + 3];
      const int n4 = so[i + 4], n5 = so[i + 5], n6 = so[i + 6], n7 = so[i + 7];
      const float v0 = zq[(size_t)n0 * 128 + t];
      const float v1 = zq[(size_t)n1 * 128 + t];
      const float v2 = zq[(size_t)n2 * 128 + t];
      const float v3 = zq[(size_t)n3 * 128 + t];
      const float v4 = zq[(size_t)n4 * 128 + t];
      const float v5 = zq[(size_t)n5 * 128 + t];
      const float v6 = zq[(size_t)n6 * 128 + t];
      const float v7 = zq[(size_t)n7 * 128 + t];
      acc += ((v0 + v1) + (v2 + v3)) + ((v4 + v5) + (v6 + v7));
      float e;
      e = cbv - v0; loss = fmaf(e, e, loss);
      e = cbv - v1; loss = fmaf(e, e, loss);
      e = cbv - v2; loss = fmaf(e, e, loss);
      e = cbv - v3; loss = fmaf(e, e, loss);
      e = cbv - v4; loss = fmaf(e, e, loss);
      e = cbv - v5; loss = fmaf(e, e, loss);
      e = cbv - v6; loss = fmaf(e, e, loss);
      e = cbv - v7; loss = fmaf(e, e, loss);
      zq[(size_t)n0 * 128 + t] = cbv; zq[(size_t)n1 * 128 + t] = cbv;
      zq[(size_t)n2 * 128 + t] = cbv; zq[(size_t)n3 * 128 + t] = cbv;
      zq[(size_t)n4 * 128 + t] = cbv; zq[(size_t)n5 * 128 + t] = cbv;
      zq[(size_t)n6 * 128 + t] = cbv; zq[(size_t)n7 * 128 + t] = cbv;
      i += 8;
    } else {
      const int kk = sk[i];
      if (kk != kprev) {
        atomicAdd(&out6[kprev * 128 + t], 0.01f * acc);
        acc = 0.f; kprev = kk;
        cbv = cb[kk * 128 + t];
      }
      const int n = so[i];
      const float v = zq[(size_t)n * 128 + t];
      acc += v;
      const float e = cbv - v; loss = fmaf(e, e, loss);
      zq[(size_t)n * 128 + t] = cbv;
      ++i;
    }
  }
  atomicAdd(&out6[kprev * 128 + t], 0.01f * acc);
#pragma unroll
  for (int m = 32; m; m >>= 1) loss += __shfl_xor(loss, m, 64);
  if ((t & 63) == 0) red[t >> 6] = loss;
  __syncthreads();
  if (t == 0) lossp[blockIdx.x] = red[0] + red[1];
}

// ---------------- new_codebook + losses (block 511 reduces partials) -------
__global__ void k_final(const float* __restrict__ out5, const float* __restrict__ out6,
                        const float* __restrict__ ntot_p, const float* __restrict__ lossp,
                        float* __restrict__ out4, float* __restrict__ out2,
                        float* __restrict__ out3) {
  __shared__ float red[4];
  const int i = blockIdx.x * blockDim.x + threadIdx.x;
  const float ntot = *ntot_p;
  const int k = i >> 7;
  const float w = (out5[k] + 1e-5f) / (ntot + KCB * 1e-5f) * ntot;
  out4[i] = out6[i] / w;
  if (blockIdx.x == 511) {
    const int t = threadIdx.x;
    float s = 0.f;
#pragma unroll
    for (int j = 0; j < NCHUNKS / 256; ++j) s += lossp[t + 256 * j];
#pragma unroll
    for (int m = 32; m; m >>= 1) s += __shfl_xor(s, m, 64);
    if ((t & 63) == 0) red[t >> 6] = s;
    __syncthreads();
    if (t == 0) {
      const float lv = (red[0] + red[1] + red[2] + red[3]) * (1.f / 8388608.f);
      *out2 = lv; *out3 = lv;
    }
  }
}

extern "C" void kernel_launch(void* const* d_in, const int* in_sizes, int n_in,
                              void* d_out, int out_size, void* d_ws, size_t ws_size,
                              hipStream_t stream) {
  (void)in_sizes; (void)n_in; (void)out_size; (void)ws_size;
  const float* z   = (const float*)d_in[0];
  const float* cb  = (const float*)d_in[1];
  const float* emc = (const float*)d_in[2];
  const float* emw = (const float*)d_in[3];
  float* out = (float*)d_out;
  float* out0 = out;                    // quantized_st  [8388608]
  float* out1 = out + 8388608;          // idx_map (float)[65536]
  float* out2 = out + 8454144;          // commitment_loss [1]
  float* out3 = out + 8454145;          // codebook_loss   [1]
  float* out4 = out + 8454146;          // new_codebook  [131072]
  float* out5 = out + 8585218;          // new_ema_count [1024]
  float* out6 = out + 8586242;          // new_ema_weight[131072]
  float* ws = (float*)d_ws;
  uint4* cbt      = (uint4*)ws;         // [16384] uint4 = 256KB
  // pcand [2*NVEC] uint2 = 1MB, aliases order/key (scatter runs after rescore)
  uint2* pcand    = (uint2*)(ws + 65536);
  int* order      = (int*)(ws + 65536); // [65536]
  int* key        = (int*)(ws + 131072);// [65536]  (pcand spans through 327680)
  float* ccb      = ws + 327680;        // [1024]
  int* hist       = (int*)(ws + 328704);// [1024]
  int* cursor     = (int*)(ws + 329728);// [1024]
  float* ntot     = ws + 330752;        // [1]
  float* lossp    = ws + 331776;        // [1024]
  double* cc64    = (double*)(ws + 333824);  // [1024] doubles (8B-aligned)
  float* z_t = out0;                    // z_t aliases out0 (overwritten in chunkreduce_q)

  hipLaunchKernelGGL(k_prep, dim3(64), dim3(256), 0, stream, cb, emw, cbt, ccb,
                     cc64, out6, hist);
  hipLaunchKernelGGL(k_argmin3t, dim3(NVEC / 64), dim3(256), 0, stream,
                     z, cbt, ccb, pcand, z_t);
  hipLaunchKernelGGL(k_rescore_hist, dim3(NVEC / 256), dim3(256), 0, stream,
                     z_t, cb, cc64, pcand, out1, hist);
  hipLaunchKernelGGL(k_scan, dim3(1), dim3(1024), 0, stream, hist, emc, cursor,
                     out5, ntot);
  hipLaunchKernelGGL(k_scatter, dim3(NVEC / 256), dim3(256), 0, stream, out1, cursor,
                     order, key);
  hipLaunchKernelGGL(k_chunkreduce_q, dim3(NCHUNKS), dim3(128), 0, stream,
                     z_t, cb, order, key, out6, lossp);
  hipLaunchKernelGGL(k_final, dim3(512), dim3(256), 0, stream, out5, out6, ntot,
                     lossp, out4, out2, out3);
}